// Round 9
// baseline (98.347 us; speedup 1.0000x reference)
//
#include <hip/hip_runtime.h>

#define IN_F 4096
#define OUT_F 11008
#define GROUPSIZE 128
#define NGROUPS 32
#define QROWS 512
#define ZCOLS 1376
#define REP 5

#define WS_OLD_BYTES ((size_t)8 * 4 * OUT_F * sizeof(float))   // 1.4 MB

__device__ __forceinline__ int opaque_zero_i() {
    int z; asm volatile("v_mov_b32 %0, 0" : "=v"(z)); return z;
}
__device__ __forceinline__ float opaque_zero_f() {
    float z; asm volatile("v_mov_b32 %0, 0" : "=v"(z)); return z;
}

// ===== Probe A: R2-structure (SMEM x path), REP reps, rep 0 is REAL =====
// grid (172, 8), block 256 = 64 cols x 4 kp. Thread = one group, one column.
__global__ __launch_bounds__(256) void probe_r2_smem(
    const float* __restrict__ x, const float* __restrict__ scales,
    const int* __restrict__ qweight, const int* __restrict__ qzeros,
    float* __restrict__ ws)            // [8, 4, OUT_F]
{
    __shared__ float part[4][4][64];
    const int tid = threadIdx.x;
    const int col = tid & 63;
    const int kp  = tid >> 6;
    const int n   = blockIdx.x * 64 + col;
    const int g   = blockIdx.y * 4 + kp;
    const int gu  = __builtin_amdgcn_readfirstlane(g);
    const unsigned qz = (unsigned)qzeros[g * ZCOLS + (n >> 3)];
    const float zf = (float)(((qz >> (4u * (unsigned)(n & 7))) & 0xFu) + 1u);
    const float sc = scales[g * OUT_F + n];
    const int kkbase = gu * (GROUPSIZE / 8);
    const int sZero  = __builtin_amdgcn_readfirstlane(opaque_zero_i());
    const float kill = opaque_zero_f();

    float ga[4] = {0.f, 0.f, 0.f, 0.f};

    #pragma unroll 1
    for (int rep = 0; rep < REP; ++rep) {
        const int kb = kkbase + rep * sZero;      // == kkbase, but opaque
        float ra[4] = {0.f, 0.f, 0.f, 0.f};
        #pragma unroll
        for (int t = 0; t < GROUPSIZE / 8; ++t) {
            const int kk = kb + t;
            const unsigned w = (unsigned)qweight[kk * OUT_F + n];
            const unsigned lo = w & 0x0F0F0F0Fu;
            const unsigned hi = (w >> 4) & 0x0F0F0F0Fu;
            float q[8];
            q[0] = (float)(lo & 0xFFu);         q[1] = (float)(hi & 0xFFu);
            q[2] = (float)((lo >> 8) & 0xFFu);  q[3] = (float)((hi >> 8) & 0xFFu);
            q[4] = (float)((lo >> 16) & 0xFFu); q[5] = (float)((hi >> 16) & 0xFFu);
            q[6] = (float)(lo >> 24);           q[7] = (float)(hi >> 24);
            const int k0 = kk * 8;
            #pragma unroll
            for (int j = 0; j < 8; ++j) {
                const float d = q[j] - zf;
                #pragma unroll
                for (int m = 0; m < 4; ++m) ra[m] += x[m * IN_F + k0 + j] * d;
            }
        }
        if (rep == 0) {
            #pragma unroll
            for (int m = 0; m < 4; ++m) ga[m] += ra[m];
        } else {
            #pragma unroll
            for (int m = 0; m < 4; ++m) ga[m] += kill * ra[m];  // keep live, adds 0
        }
    }

    #pragma unroll
    for (int m = 0; m < 4; ++m) part[kp][m][col] = sc * ga[m];
    __syncthreads();
    const int m = tid >> 6;
    const int c = tid & 63;
    const int nn = blockIdx.x * 64 + c;
    const float s = part[0][m][c] + part[1][m][c] + part[2][m][c] + part[3][m][c];
    ws[(blockIdx.y * 4 + m) * OUT_F + nn] = s;
}

// ===== Probe B: R8-structure (register x path), REP reps, ALL dummy =====
// grid (172, 32), block 256 = 16 rows x 16 col-quads. Writes into the same
// 1.4 MB ws region (g&7) BEFORE probe A overwrites it -> output unaffected.
__global__ __launch_bounds__(256) void probe_r8_reg(
    const float* __restrict__ x, const float* __restrict__ scales,
    const int* __restrict__ qweight, const int* __restrict__ qzeros,
    float* __restrict__ ws)
{
    __shared__ float part[16][4][64];
    const int tid = threadIdx.x;
    const int rl  = tid >> 4;
    const int cq  = tid & 15;
    const int bx  = blockIdx.x;
    const int g   = blockIdx.y;
    const int c0  = bx * 64 + cq * 4;
    const int row = g * 16 + rl;

    const unsigned qz = (unsigned)qzeros[g * ZCOLS + (c0 >> 3)];
    const float4 s4 = *(const float4*)(scales + g * OUT_F + c0);
    const unsigned bsh = 4u * (unsigned)(c0 & 7);
    const int vZero = opaque_zero_i();
    const float kill = opaque_zero_f();

    float acc[4][4];
    #pragma unroll
    for (int m = 0; m < 4; ++m)
        #pragma unroll
        for (int c = 0; c < 4; ++c) acc[m][c] = 0.f;

    #pragma unroll 1
    for (int rep = 0; rep < REP; ++rep) {
        const int row2 = row + rep * vZero;       // == row, but opaque
        const int k0   = row2 * 8;
        const int4 w4 = *(const int4*)(qweight + (size_t)row2 * OUT_F + c0);
        float4 xa[4], xb[4];
        #pragma unroll
        for (int m = 0; m < 4; ++m) {
            xa[m] = *(const float4*)(x + m * IN_F + k0);
            xb[m] = *(const float4*)(x + m * IN_F + k0 + 4);
        }
        const unsigned wv[4] = {(unsigned)w4.x, (unsigned)w4.y,
                                (unsigned)w4.z, (unsigned)w4.w};
        float ra[4][4];
        #pragma unroll
        for (int m = 0; m < 4; ++m)
            #pragma unroll
            for (int c = 0; c < 4; ++c) ra[m][c] = 0.f;

        #pragma unroll
        for (int c = 0; c < 4; ++c) {
            const float z = (float)(((qz >> (bsh + 4u * c)) & 0xFu) + 1u);
            const unsigned w  = wv[c];
            const unsigned lo = w & 0x0F0F0F0Fu;
            const unsigned hi = (w >> 4) & 0x0F0F0F0Fu;
            float d[8];
            d[0] = (float)(lo & 0xFFu) - z;          d[1] = (float)(hi & 0xFFu) - z;
            d[2] = (float)((lo >> 8) & 0xFFu) - z;   d[3] = (float)((hi >> 8) & 0xFFu) - z;
            d[4] = (float)((lo >> 16) & 0xFFu) - z;  d[5] = (float)((hi >> 16) & 0xFFu) - z;
            d[6] = (float)(lo >> 24) - z;            d[7] = (float)(hi >> 24) - z;
            #pragma unroll
            for (int m = 0; m < 4; ++m) {
                ra[m][c] += xa[m].x * d[0];
                ra[m][c] += xa[m].y * d[1];
                ra[m][c] += xa[m].z * d[2];
                ra[m][c] += xa[m].w * d[3];
                ra[m][c] += xb[m].x * d[4];
                ra[m][c] += xb[m].y * d[5];
                ra[m][c] += xb[m].z * d[6];
                ra[m][c] += xb[m].w * d[7];
            }
        }
        #pragma unroll
        for (int m = 0; m < 4; ++m)
            #pragma unroll
            for (int c = 0; c < 4; ++c) acc[m][c] += kill * ra[m][c];
    }

    #pragma unroll
    for (int m = 0; m < 4; ++m) {
        float4 r;
        r.x = acc[m][0] * s4.x;
        r.y = acc[m][1] * s4.y;
        r.z = acc[m][2] * s4.z;
        r.w = acc[m][3] * s4.w;
        *(float4*)&part[rl][m][cq * 4] = r;
    }
    __syncthreads();
    const int m   = tid >> 6;
    const int col = tid & 63;
    float t0 = 0.f;
    #pragma unroll
    for (int r = 0; r < 16; ++r) t0 += part[r][m][col];
    ws[(size_t)((g & 7) * 4 + m) * OUT_F + bx * 64 + col] = t0;   // scratch, overwritten
}

// ===== Stage 2 (proven) =====
__global__ __launch_bounds__(256) void gptq_reduce8(
    const float* __restrict__ ws, const float* __restrict__ bias,
    float* __restrict__ out)
{
    const int n = blockIdx.x * 256 + threadIdx.x;
    const int m = blockIdx.y;
    float s = bias[n];
    #pragma unroll
    for (int ks = 0; ks < 8; ++ks) s += ws[(ks * 4 + m) * OUT_F + n];
    out[m * OUT_F + n] = s;
}

// ===== Fallback (no ws): R1-style fused =====
__global__ __launch_bounds__(256) void gptq_gemv_fused(
    const float* __restrict__ x, const float* __restrict__ scales,
    const float* __restrict__ bias, const int* __restrict__ qweight,
    const int* __restrict__ qzeros, float* __restrict__ out)
{
    __shared__ float part[4][4][64];
    const int tid = threadIdx.x;
    const int col = tid & 63;
    const int kp  = tid >> 6;
    const int n   = blockIdx.x * 64 + col;
    const unsigned zshift = 4u * (unsigned)(n & 7);
    const int zcol = n >> 3;
    float acc[4] = {0.f, 0.f, 0.f, 0.f};
    for (int g = kp * 8; g < kp * 8 + 8; ++g) {
        const unsigned qz = (unsigned)qzeros[g * ZCOLS + zcol];
        const float zf = (float)(((qz >> zshift) & 0xFu) + 1u);
        const float sc = scales[g * OUT_F + n];
        float ga[4] = {0.f, 0.f, 0.f, 0.f};
        #pragma unroll 4
        for (int t = 0; t < 16; ++t) {
            const int kk = g * 16 + t;
            const unsigned w = (unsigned)qweight[kk * OUT_F + n];
            const unsigned lo = w & 0x0F0F0F0Fu;
            const unsigned hi = (w >> 4) & 0x0F0F0F0Fu;
            float q[8];
            q[0] = (float)(lo & 0xFFu);         q[1] = (float)(hi & 0xFFu);
            q[2] = (float)((lo >> 8) & 0xFFu);  q[3] = (float)((hi >> 8) & 0xFFu);
            q[4] = (float)((lo >> 16) & 0xFFu); q[5] = (float)((hi >> 16) & 0xFFu);
            q[6] = (float)(lo >> 24);           q[7] = (float)(hi >> 24);
            const int k0 = kk * 8;
            #pragma unroll
            for (int j = 0; j < 8; ++j) {
                const float d = q[j] - zf;
                #pragma unroll
                for (int m = 0; m < 4; ++m) ga[m] += x[m * IN_F + k0 + j] * d;
            }
        }
        #pragma unroll
        for (int m = 0; m < 4; ++m) acc[m] += sc * ga[m];
    }
    #pragma unroll
    for (int m = 0; m < 4; ++m) part[kp][m][col] = acc[m];
    __syncthreads();
    const int m = tid >> 6;
    const int c = tid & 63;
    const int nn = blockIdx.x * 64 + c;
    const float s = part[0][m][c] + part[1][m][c] + part[2][m][c] + part[3][m][c];
    out[m * OUT_F + nn] = s + bias[nn];
}

extern "C" void kernel_launch(void* const* d_in, const int* in_sizes, int n_in,
                              void* d_out, int out_size, void* d_ws, size_t ws_size,
                              hipStream_t stream) {
    const float* x       = (const float*)d_in[0];
    const float* scales  = (const float*)d_in[1];
    const float* bias    = (const float*)d_in[2];
    const int*   qweight = (const int*)d_in[3];
    const int*   qzeros  = (const int*)d_in[4];
    float*       out     = (float*)d_out;

    if (ws_size >= WS_OLD_BYTES) {
        float* ws = (float*)d_ws;
        // diagnostic probe (dummy results, scratch writes overwritten below)
        dim3 gB(OUT_F / 64, NGROUPS);
        probe_r8_reg<<<gB, 256, 0, stream>>>(x, scales, qweight, qzeros, ws);
        // real stage 1 (R2 structure, REP loop with rep0 real)
        dim3 gA(OUT_F / 64, 8);
        probe_r2_smem<<<gA, 256, 0, stream>>>(x, scales, qweight, qzeros, ws);
        dim3 g2(OUT_F / 256, 4);
        gptq_reduce8<<<g2, 256, 0, stream>>>(ws, bias, out);
    } else {
        dim3 grid(OUT_F / 64);
        gptq_gemv_fused<<<grid, 256, 0, stream>>>(x, scales, bias, qweight, qzeros, out);
    }
}